// Round 2
// baseline (137.776 us; speedup 1.0000x reference)
//
#include <hip/hip_runtime.h>

// b=16, n=m=2048, d=dv=128, fp32 in/out, temp=sqrt(128).
// Prep: K -> bf16 scaled by log2e/temp; V -> Vt[b][dv][m] bf16. Q cast in-kernel.
// Attention: swapped S^T = K.Q^T via 32x32x16 bf16 MFMA, P = exp2(S),
// P->A-frag via v_cvt_pk_bf16_f32 + v_permlane32_swap_b32 (in-register).
// 2-tile software pipeline per wave: QK(t+1) || softmax(t) || PV(t).
// V(t) is read to registers BEFORE the barrier so STAGE(t+2) can overwrite
// its buffer right after -> still ONE barrier per tile, prefetch in flight
// across the whole compute body. QK accumulation split into two 4-deep
// chains to halve MFMA dependency latency.
// Block = 4 waves: 2 q-waves (BQ=64) x 2 m-waves (BK=64 split 32/32).
// Grid 16x32 = 512 blocks -> 2 blocks/CU (64KB LDS), 8 waves/CU.

#define BATCH 16
#define SEQ   2048
#define DIM   128
#define NT    (SEQ / 64)

typedef short bf16x8 __attribute__((ext_vector_type(8)));
typedef float f32x16 __attribute__((ext_vector_type(16)));

static __device__ __forceinline__ unsigned pk2(float lo, float hi) {
  union { float f; unsigned u; } a, b;
  a.f = lo; b.f = hi;
  return ((b.u + 0x8000u) & 0xffff0000u) | ((a.u + 0x8000u) >> 16);
}
static __device__ __forceinline__ float fast_exp2(float x) {
#if __has_builtin(__builtin_amdgcn_exp2f)
  return __builtin_amdgcn_exp2f(x);
#else
  return exp2f(x);
#endif
}

typedef __attribute__((address_space(1))) const unsigned int g_u32;
typedef __attribute__((address_space(3))) unsigned int l_u32;
static __device__ __forceinline__ void gl2lds16(const unsigned short* g, unsigned short* l) {
  __builtin_amdgcn_global_load_lds((g_u32*)g, (l_u32*)l, 16, 0, 0);
}

// ---- fused preprocess: blocks [0,2048): K cvt+scale; [2048,3072): V transpose ----
__global__ __launch_bounds__(256)
void prep_kernel(const float* __restrict__ K, const float* __restrict__ V,
                 unsigned short* __restrict__ Kb, unsigned short* __restrict__ Vt,
                 float scale) {
  const int bx = blockIdx.x, tid = threadIdx.x;
  if (bx < 2048) {
    size_t idx = (size_t)bx * 256 + tid;
    const float4* kf = (const float4*)K;
    float4 a = kf[idx * 2], c = kf[idx * 2 + 1];
    uint4 o;
    o.x = pk2(a.x * scale, a.y * scale);
    o.y = pk2(a.z * scale, a.w * scale);
    o.z = pk2(c.x * scale, c.y * scale);
    o.w = pk2(c.z * scale, c.w * scale);
    ((uint4*)Kb)[idx] = o;
  } else {
    __shared__ float tile[128][33];
    const int vb = bx - 2048;                 // 1024 blocks
    const int b = vb >> 6, r = vb & 63;
    const int m0 = (r & 15) * 128, d0 = (r >> 4) * 32;
    const int c = tid & 7, mr = tid >> 3;
    const float* src = V + ((size_t)(b * SEQ) + m0) * DIM + d0;
#pragma unroll
    for (int it = 0; it < 4; ++it) {
      int m = it * 32 + mr;
      float4 x = *(const float4*)(src + (size_t)m * DIM + c * 4);
      tile[m][c * 4 + 0] = x.x; tile[m][c * 4 + 1] = x.y;
      tile[m][c * 4 + 2] = x.z; tile[m][c * 4 + 3] = x.w;
    }
    __syncthreads();
    const int dr = tid >> 3, s = tid & 7;
    unsigned short* dst = Vt + ((size_t)(b * DIM) + d0 + dr) * SEQ + m0;
#pragma unroll
    for (int it = 0; it < 2; ++it) {
      int slot = it * 8 + s;
      uint4 o;
      o.x = pk2(tile[slot * 8 + 0][dr], tile[slot * 8 + 1][dr]);
      o.y = pk2(tile[slot * 8 + 2][dr], tile[slot * 8 + 3][dr]);
      o.z = pk2(tile[slot * 8 + 4][dr], tile[slot * 8 + 5][dr]);
      o.w = pk2(tile[slot * 8 + 6][dr], tile[slot * 8 + 7][dr]);
      *(uint4*)(dst + slot * 8) = o;
    }
  }
}

// ---- main flash attention ----
// LDS (bytes): K bufs [0,16384) [16384,32768); V bufs [32768,49152) [49152,65536)
// K buf: 64 rows x 256B linear, [row][x] holds K[m0+row][x ^ ((row&15)<<4)]
// V buf: 128 rows x 128B linear, [row][x] holds Vt[row][m0 + (x ^ ((row&7)<<4))/2]
// Epilogue (after barrier) aliases: cb f32[2][4096] @0, cbL f32[2][64] @32768.

__global__ __launch_bounds__(256, 2)
void attn_kernel(const float* __restrict__ Qf,
                 const unsigned short* __restrict__ Kb,
                 const unsigned short* __restrict__ Vtb,
                 float* __restrict__ out) {
  __shared__ __align__(1024) unsigned char smem[65536];
  unsigned short* sm16 = (unsigned short*)smem;

  const int tid  = threadIdx.x;
  const int wv   = tid >> 6;
  const int w_q  = wv & 1;                  // q-subtile (32 rows)
  const int w_m  = wv >> 1;                 // m-half (32 cols) of the 64-tile
  const int lane = tid & 63;
  const int l31  = lane & 31;
  const int q2   = lane >> 5;
  const int b    = blockIdx.x;
  const int q0   = blockIdx.y * 64 + w_q * 32;

  const unsigned short* kb = Kb  + (size_t)b * SEQ * DIM;   // [m][d], pre-scaled
  const unsigned short* vb = Vtb + (size_t)b * SEQ * DIM;   // [dv][m]

  // Q fragments (B-operand of swapped QK^T)
  bf16x8 aq[8];
  {
    const float* qp = Qf + ((size_t)(b * SEQ) + q0 + l31) * DIM + q2 * 8;
#pragma unroll
    for (int c = 0; c < 8; ++c) {
      float4 x = *(const float4*)(qp + c * 16);
      float4 y = *(const float4*)(qp + c * 16 + 4);
      union { unsigned i[4]; bf16x8 v; } u;
      u.i[0] = pk2(x.x, x.y); u.i[1] = pk2(x.z, x.w);
      u.i[2] = pk2(y.x, y.y); u.i[3] = pk2(y.z, y.w);
      aq[c] = u.v;
    }
  }

  // staging source offsets (ushort units); LDS dest linear, global src pre-swizzled
  unsigned kgo[4], vgo[4];
#pragma unroll
  for (int i = 0; i < 4; ++i) {
    int ch = wv * 4 + i;
    int krow = ch * 4 + (lane >> 4);
    kgo[i] = (unsigned)(krow * 128) + ((((lane & 15) << 4) ^ ((krow & 15) << 4)) >> 1);
    int vrow = ch * 8 + (lane >> 3);
    vgo[i] = (unsigned)(vrow * 2048) + ((((lane & 7) << 4) ^ ((vrow & 7) << 4)) >> 1);
  }

  // swizzled read base offsets (bytes, within a buffer)
  const int kro = ((w_m * 32 + l31) << 8) + ((q2 << 4) ^ ((l31 & 15) << 4));
  const int vro = (l31 << 7) + (((w_m << 6) + (q2 << 4)) ^ ((l31 & 7) << 4));

  f32x16 oacc[4];
#pragma unroll
  for (int t = 0; t < 4; ++t)
#pragma unroll
    for (int i = 0; i < 16; ++i) oacc[t][i] = 0.0f;
  float ls[4] = {0.0f, 0.0f, 0.0f, 0.0f};

#define STAGE(TK, BUF) do {                                                  \
    const unsigned short* kt_b = kb + ((size_t)(TK) << 13);                  \
    const unsigned short* vt_b = vb + ((TK) << 6);                           \
    unsigned short* kd = sm16 + (((BUF) + wv * 4096) >> 1);                  \
    unsigned short* vd = sm16 + ((32768 + (BUF) + wv * 4096) >> 1);          \
    _Pragma("unroll")                                                        \
    for (int i = 0; i < 4; ++i) gl2lds16(kt_b + kgo[i], kd + i * 512);       \
    _Pragma("unroll")                                                        \
    for (int i = 0; i < 4; ++i) gl2lds16(vt_b + vgo[i], vd + i * 512);       \
  } while (0)

#define VLOAD(CUR) do {                                                      \
    const unsigned char* vB_ = smem + 32768 + (CUR);                         \
    _Pragma("unroll")                                                        \
    for (int t = 0; t < 4; ++t) {                                            \
      vr[2 * t]     = *(const bf16x8*)(vB_ + t * 4096 + vro);                \
      vr[2 * t + 1] = *(const bf16x8*)(vB_ + t * 4096 + (vro ^ 32));         \
    }                                                                        \
  } while (0)

  // QK: two independent 4-deep MFMA chains, merged at the end
#define QK(CUR, SD) do {                                                     \
    const unsigned char* kB_ = smem + (CUR);                                 \
    f32x16 se, so;                                                           \
    _Pragma("unroll")                                                        \
    for (int i = 0; i < 16; ++i) { se[i] = 0.0f; so[i] = 0.0f; }             \
    __builtin_amdgcn_s_setprio(1);                                           \
    _Pragma("unroll")                                                        \
    for (int c = 0; c < 4; ++c) {                                            \
      bf16x8 b0 = *(const bf16x8*)(kB_ + (kro ^ ((2 * c) << 5)));            \
      se = __builtin_amdgcn_mfma_f32_32x32x16_bf16(b0, aq[2 * c], se, 0, 0, 0); \
      bf16x8 b1 = *(const bf16x8*)(kB_ + (kro ^ ((2 * c + 1) << 5)));        \
      so = __builtin_amdgcn_mfma_f32_32x32x16_bf16(b1, aq[2 * c + 1], so, 0, 0, 0); \
    }                                                                        \
    __builtin_amdgcn_s_setprio(0);                                           \
    _Pragma("unroll")                                                        \
    for (int i = 0; i < 16; ++i) SD[i] = se[i] + so[i];                      \
  } while (0)

#define SOFTMAX(S, PU0, PU1) do {                                            \
    float p[16];                                                             \
    _Pragma("unroll")                                                        \
    for (int i = 0; i < 16; ++i) p[i] = fast_exp2(S[i]);                     \
    _Pragma("unroll")                                                        \
    for (int i = 0; i < 4; ++i) {                                            \
      ls[0] += p[4 * i + 0]; ls[1] += p[4 * i + 1];                          \
      ls[2] += p[4 * i + 2]; ls[3] += p[4 * i + 3];                          \
    }                                                                        \
    unsigned d0, d1, d2, d3, d4, d5, d6, d7;                                 \
    asm("v_cvt_pk_bf16_f32 %0, %1, %2" : "=v"(d0) : "v"(p[0]),  "v"(p[1]));  \
    asm("v_cvt_pk_bf16_f32 %0, %1, %2" : "=v"(d1) : "v"(p[2]),  "v"(p[3]));  \
    asm("v_cvt_pk_bf16_f32 %0, %1, %2" : "=v"(d2) : "v"(p[4]),  "v"(p[5]));  \
    asm("v_cvt_pk_bf16_f32 %0, %1, %2" : "=v"(d3) : "v"(p[6]),  "v"(p[7]));  \
    asm("v_cvt_pk_bf16_f32 %0, %1, %2" : "=v"(d4) : "v"(p[8]),  "v"(p[9]));  \
    asm("v_cvt_pk_bf16_f32 %0, %1, %2" : "=v"(d5) : "v"(p[10]), "v"(p[11])); \
    asm("v_cvt_pk_bf16_f32 %0, %1, %2" : "=v"(d6) : "v"(p[12]), "v"(p[13])); \
    asm("v_cvt_pk_bf16_f32 %0, %1, %2" : "=v"(d7) : "v"(p[14]), "v"(p[15])); \
    asm("v_permlane32_swap_b32 %0, %1" : "+v"(d0), "+v"(d2));                \
    asm("v_permlane32_swap_b32 %0, %1" : "+v"(d1), "+v"(d3));                \
    asm("v_permlane32_swap_b32 %0, %1" : "+v"(d4), "+v"(d6));                \
    asm("v_permlane32_swap_b32 %0, %1" : "+v"(d5), "+v"(d7));                \
    PU0.u[0] = d0; PU0.u[1] = d1; PU0.u[2] = d2; PU0.u[3] = d3;              \
    PU1.u[0] = d4; PU1.u[1] = d5; PU1.u[2] = d6; PU1.u[3] = d7;              \
  } while (0)

#define PV(PU0, PU1) do {                                                    \
    __builtin_amdgcn_s_setprio(1);                                           \
    _Pragma("unroll")                                                        \
    for (int t = 0; t < 4; ++t) {                                            \
      oacc[t] = __builtin_amdgcn_mfma_f32_32x32x16_bf16(PU0.v, vr[2 * t], oacc[t], 0, 0, 0); \
      oacc[t] = __builtin_amdgcn_mfma_f32_32x32x16_bf16(PU1.v, vr[2 * t + 1], oacc[t], 0, 0, 0); \
    }                                                                        \
    __builtin_amdgcn_s_setprio(0);                                           \
  } while (0)

  bf16x8 vr[8];
  f32x16 sA, sB;

  // prologue: stage tiles 0,1; compute QK(0)
  STAGE(0, 0);
  __syncthreads();
  STAGE(1, 16384);
  QK(0, sA);

  // steady state: one barrier per tile; per body: VLOAD(t) -> barrier ->
  // STAGE(t+2) -> QK(t+1) || SOFTMAX(t) -> PV(t)
#pragma unroll 1
  for (int t = 0; t < NT - 2; t += 2) {
    {
      VLOAD(0);
      __syncthreads();
      STAGE(t + 2, 0);
      QK(16384, sB);
      union { unsigned u[4]; bf16x8 v; } pu0, pu1;
      SOFTMAX(sA, pu0, pu1);
      PV(pu0, pu1);
    }
    {
      VLOAD(16384);
      __syncthreads();
      STAGE(t + 3, 16384);
      QK(0, sA);
      union { unsigned u[4]; bf16x8 v; } pu0, pu1;
      SOFTMAX(sB, pu0, pu1);
      PV(pu0, pu1);
    }
  }
  // tail: tiles NT-2, NT-1 (no further staging / QK)
  {
    VLOAD(0);
    __syncthreads();
    QK(16384, sB);
    union { unsigned u[4]; bf16x8 v; } pu0, pu1;
    SOFTMAX(sA, pu0, pu1);
    PV(pu0, pu1);
  }
  {
    VLOAD(16384);
    union { unsigned u[4]; bf16x8 v; } pu0, pu1;
    SOFTMAX(sB, pu0, pu1);
    PV(pu0, pu1);
  }

#undef STAGE
#undef VLOAD
#undef QK
#undef SOFTMAX
#undef PV

  float lsum = (ls[0] + ls[1]) + (ls[2] + ls[3]);
  // merge q2 halves of the row sum
  lsum += __shfl_xor(lsum, 32, 64);

  // combine the two m-halves through LDS, normalize, store
  __syncthreads();                          // all tile reads done before aliasing
  float* cb  = (float*)smem;                // [2][64][64] partials = 32768 B
  float* cbL = (float*)(smem + 32768);      // [2][64] row sums
  if (w_m == 1) {
    float* my = cb + w_q * 4096;
#pragma unroll
    for (int t = 0; t < 4; ++t)
#pragma unroll
      for (int r = 0; r < 16; ++r)
        my[(t * 16 + r) * 64 + lane] = oacc[t][r];
  }
  cbL[w_m * 64 + w_q * 32 + l31] = lsum;
  __syncthreads();
  if (w_m == 0) {
    const float* pr = cb + w_q * 4096;
    float linv[16];
#pragma unroll
    for (int r = 0; r < 16; ++r) {
      int qr = (r & 3) + ((r >> 2) << 3) + (q2 << 2);
      linv[r] = 1.0f / (cbL[w_q * 32 + qr] + cbL[64 + w_q * 32 + qr]);
    }
    float* ob = out + ((size_t)(b * SEQ) + q0) * DIM;
#pragma unroll
    for (int t = 0; t < 4; ++t)
#pragma unroll
      for (int r = 0; r < 16; ++r) {
        int qr = (r & 3) + ((r >> 2) << 3) + (q2 << 2);
        ob[(size_t)qr * DIM + t * 32 + l31] = (oacc[t][r] + pr[(t * 16 + r) * 64 + lane]) * linv[r];
      }
  }
}

extern "C" void kernel_launch(void* const* d_in, const int* in_sizes, int n_in,
                              void* d_out, int out_size, void* d_ws, size_t ws_size,
                              hipStream_t stream) {
  const float* Q = (const float*)d_in[0];
  const float* K = (const float*)d_in[1];
  const float* V = (const float*)d_in[2];
  float* out = (float*)d_out;

  const size_t elems = (size_t)BATCH * SEQ * DIM;   // 4,194,304
  unsigned short* Kb = (unsigned short*)d_ws;       // 8 MB
  unsigned short* Vt = Kb + elems;                  // 8 MB (ws >= 16 MB)

  const double TEMPERATURE = 11.313708498984761;
  const float scale = (float)(1.4426950408889634 / TEMPERATURE);  // log2(e)/temp on K

  prep_kernel<<<3072, 256, 0, stream>>>(K, V, Kb, Vt, scale);
  attn_kernel<<<dim3(BATCH, SEQ / 64), 256, 0, stream>>>(Q, Kb, Vt, out);
}

// Round 3
// 135.068 us; speedup vs baseline: 1.0200x; 1.0200x over previous
//
#include <hip/hip_runtime.h>

// b=16, n=m=2048, d=dv=128, fp32 in/out, temp=sqrt(128).
// Prep: K -> bf16 scaled by log2e/temp; V -> Vt[b][dv][m] bf16. Q cast in-kernel.
// Attention: swapped S^T = K.Q^T via 32x32x16 bf16 MFMA (lane holds one q-row's
// 16 m-values), P = exp2(S), P->A-frag via v_cvt_pk_bf16_f32 +
// v_permlane32_swap_b32 (no LDS roundtrip), PV accumulate.
// K/V staged by global_load_lds (linear LDS dest, XOR-swizzled global source;
// reads apply same XOR). Double-buffered, ONE barrier per tile; STAGE(t+1)
// issued right after the barrier stays in flight across the whole compute body.
// Round-3 deltas vs round-1 (state-neutral only; round-2's 2-tile pipeline
// spilled — WRITE_SIZE +5.6MB — and regressed):
//  - QK accumulation split into two independent 4-deep MFMA chains (se/so)
//  - softmax pack via v_cvt_pk_bf16_f32 (was 5-op manual pk2 x8)
//  - lsum kept as 4 partial accumulators
// Block = 4 waves: 2 q-waves (BQ=64) x 2 m-waves (BK=64 split 32/32).
// Grid 16x32 = 512 blocks -> 2 blocks/CU (64KB LDS), 8 waves/CU.

#define BATCH 16
#define SEQ   2048
#define DIM   128
#define NT    (SEQ / 64)

typedef short bf16x8 __attribute__((ext_vector_type(8)));
typedef float f32x16 __attribute__((ext_vector_type(16)));

static __device__ __forceinline__ unsigned pk2(float lo, float hi) {
  union { float f; unsigned u; } a, b;
  a.f = lo; b.f = hi;
  return ((b.u + 0x8000u) & 0xffff0000u) | ((a.u + 0x8000u) >> 16);
}
static __device__ __forceinline__ float fast_exp2(float x) {
#if __has_builtin(__builtin_amdgcn_exp2f)
  return __builtin_amdgcn_exp2f(x);
#else
  return exp2f(x);
#endif
}

typedef __attribute__((address_space(1))) const unsigned int g_u32;
typedef __attribute__((address_space(3))) unsigned int l_u32;
static __device__ __forceinline__ void gl2lds16(const unsigned short* g, unsigned short* l) {
  // per-lane global src; wave-uniform LDS base, HW writes base + lane*16
  __builtin_amdgcn_global_load_lds((g_u32*)g, (l_u32*)l, 16, 0, 0);
}

// ---- fused preprocess: blocks [0,2048): K cvt+scale; [2048,3072): V transpose ----
__global__ __launch_bounds__(256)
void prep_kernel(const float* __restrict__ K, const float* __restrict__ V,
                 unsigned short* __restrict__ Kb, unsigned short* __restrict__ Vt,
                 float scale) {
  const int bx = blockIdx.x, tid = threadIdx.x;
  if (bx < 2048) {
    size_t idx = (size_t)bx * 256 + tid;
    const float4* kf = (const float4*)K;
    float4 a = kf[idx * 2], c = kf[idx * 2 + 1];
    uint4 o;
    o.x = pk2(a.x * scale, a.y * scale);
    o.y = pk2(a.z * scale, a.w * scale);
    o.z = pk2(c.x * scale, c.y * scale);
    o.w = pk2(c.z * scale, c.w * scale);
    ((uint4*)Kb)[idx] = o;
  } else {
    __shared__ float tile[128][33];
    const int vb = bx - 2048;                 // 1024 blocks
    const int b = vb >> 6, r = vb & 63;
    const int m0 = (r & 15) * 128, d0 = (r >> 4) * 32;
    const int c = tid & 7, mr = tid >> 3;
    const float* src = V + ((size_t)(b * SEQ) + m0) * DIM + d0;
#pragma unroll
    for (int it = 0; it < 4; ++it) {
      int m = it * 32 + mr;
      float4 x = *(const float4*)(src + (size_t)m * DIM + c * 4);
      tile[m][c * 4 + 0] = x.x; tile[m][c * 4 + 1] = x.y;
      tile[m][c * 4 + 2] = x.z; tile[m][c * 4 + 3] = x.w;
    }
    __syncthreads();
    const int dr = tid >> 3, s = tid & 7;
    unsigned short* dst = Vt + ((size_t)(b * DIM) + d0 + dr) * SEQ + m0;
#pragma unroll
    for (int it = 0; it < 2; ++it) {
      int slot = it * 8 + s;
      uint4 o;
      o.x = pk2(tile[slot * 8 + 0][dr], tile[slot * 8 + 1][dr]);
      o.y = pk2(tile[slot * 8 + 2][dr], tile[slot * 8 + 3][dr]);
      o.z = pk2(tile[slot * 8 + 4][dr], tile[slot * 8 + 5][dr]);
      o.w = pk2(tile[slot * 8 + 6][dr], tile[slot * 8 + 7][dr]);
      *(uint4*)(dst + slot * 8) = o;
    }
  }
}

// ---- main flash attention ----
// LDS (bytes): K bufs [0,16384) [16384,32768); V bufs [32768,49152) [49152,65536)
// K buf: 64 rows x 256B linear, [row][x] holds K[m0+row][x ^ ((row&15)<<4)]
// V buf: 128 rows x 128B linear, [row][x] holds Vt[row][m0 + (x ^ ((row&7)<<4))/2]
// Epilogue (after barrier) aliases: cb f32[2][4096] @0, cbL f32[2][64] @32768.

__global__ __launch_bounds__(256, 2)
void attn_kernel(const float* __restrict__ Qf,
                 const unsigned short* __restrict__ Kb,
                 const unsigned short* __restrict__ Vtb,
                 float* __restrict__ out) {
  __shared__ __align__(1024) unsigned char smem[65536];
  unsigned short* sm16 = (unsigned short*)smem;

  const int tid  = threadIdx.x;
  const int wv   = tid >> 6;
  const int w_q  = wv & 1;                  // q-subtile (32 rows)
  const int w_m  = wv >> 1;                 // m-half (32 cols) of the 64-tile
  const int lane = tid & 63;
  const int l31  = lane & 31;
  const int q2   = lane >> 5;
  const int b    = blockIdx.x;
  const int q0   = blockIdx.y * 64 + w_q * 32;

  const unsigned short* kb = Kb  + (size_t)b * SEQ * DIM;   // [m][d], pre-scaled
  const unsigned short* vb = Vtb + (size_t)b * SEQ * DIM;   // [dv][m]

  // Q fragments (B-operand of swapped QK^T): lane (l31,q2) holds Q[q0+l31][c*16+q2*8+j]
  bf16x8 aq[8];
  {
    const float* qp = Qf + ((size_t)(b * SEQ) + q0 + l31) * DIM + q2 * 8;
#pragma unroll
    for (int c = 0; c < 8; ++c) {
      float4 x = *(const float4*)(qp + c * 16);
      float4 y = *(const float4*)(qp + c * 16 + 4);
      union { unsigned i[4]; bf16x8 v; } u;
      u.i[0] = pk2(x.x, x.y); u.i[1] = pk2(x.z, x.w);
      u.i[2] = pk2(y.x, y.y); u.i[3] = pk2(y.z, y.w);
      aq[c] = u.v;
    }
  }

  // staging source offsets (ushort units); LDS dest linear, global src pre-swizzled
  unsigned kgo[4], vgo[4];
#pragma unroll
  for (int i = 0; i < 4; ++i) {
    int ch = wv * 4 + i;
    int krow = ch * 4 + (lane >> 4);
    kgo[i] = (unsigned)(krow * 128) + ((((lane & 15) << 4) ^ ((krow & 15) << 4)) >> 1);
    int vrow = ch * 8 + (lane >> 3);
    vgo[i] = (unsigned)(vrow * 2048) + ((((lane & 7) << 4) ^ ((vrow & 7) << 4)) >> 1);
  }

  // swizzled read base offsets (bytes, within a buffer)
  const int kro = ((w_m * 32 + l31) << 8) + ((q2 << 4) ^ ((l31 & 15) << 4));
  const int vro = (l31 << 7) + (((w_m << 6) + (q2 << 4)) ^ ((l31 & 7) << 4));

  f32x16 oacc[4];
#pragma unroll
  for (int t = 0; t < 4; ++t)
#pragma unroll
    for (int i = 0; i < 16; ++i) oacc[t][i] = 0.0f;
  float ls[4] = {0.0f, 0.0f, 0.0f, 0.0f};

#define STAGE(TK, BUF) do {                                                  \
    const unsigned short* kt_b = kb + ((size_t)(TK) << 13);                  \
    const unsigned short* vt_b = vb + ((TK) << 6);                           \
    unsigned short* kd = sm16 + (((BUF) + wv * 4096) >> 1);                  \
    unsigned short* vd = sm16 + ((32768 + (BUF) + wv * 4096) >> 1);          \
    _Pragma("unroll")                                                        \
    for (int i = 0; i < 4; ++i) gl2lds16(kt_b + kgo[i], kd + i * 512);       \
    _Pragma("unroll")                                                        \
    for (int i = 0; i < 4; ++i) gl2lds16(vt_b + vgo[i], vd + i * 512);       \
  } while (0)

  STAGE(0, 0);

  for (int kt = 0; kt < NT; ++kt) {
    const int cur = (kt & 1) << 14;
    __syncthreads();                        // implicit vmcnt(0): tile kt landed;
                                            // also closes prev reads of other buf
    if (kt + 1 < NT) STAGE(kt + 1, 16384 - cur);   // in flight across compute

    const unsigned char* kB = smem + cur;
    const unsigned char* vB = smem + 32768 + cur;

    // S^T = K . Q^T : two independent 4-deep MFMA chains, merged at the end.
    // lane (l31,q2) holds S[q=l31][m=(r&3)+8*(r>>2)+4*q2]
    f32x16 se, so;
#pragma unroll
    for (int i = 0; i < 16; ++i) { se[i] = 0.0f; so[i] = 0.0f; }
    __builtin_amdgcn_s_setprio(1);
#pragma unroll
    for (int c = 0; c < 4; ++c) {
      bf16x8 b0 = *(const bf16x8*)(kB + (kro ^ ((2 * c) << 5)));
      se = __builtin_amdgcn_mfma_f32_32x32x16_bf16(b0, aq[2 * c], se, 0, 0, 0);
      bf16x8 b1 = *(const bf16x8*)(kB + (kro ^ ((2 * c + 1) << 5)));
      so = __builtin_amdgcn_mfma_f32_32x32x16_bf16(b1, aq[2 * c + 1], so, 0, 0, 0);
    }
    __builtin_amdgcn_s_setprio(0);

    // P = exp2(S); partial row sums in 4 independent accumulators
    float p[16];
#pragma unroll
    for (int i = 0; i < 16; ++i) p[i] = fast_exp2(se[i] + so[i]);
#pragma unroll
    for (int i = 0; i < 4; ++i) {
      ls[0] += p[4 * i + 0]; ls[1] += p[4 * i + 1];
      ls[2] += p[4 * i + 2]; ls[3] += p[4 * i + 3];
    }

    // P -> PV A-fragments fully in-register: cvt_pk pairs + permlane32_swap
    unsigned d0, d1, d2, d3, d4, d5, d6, d7;
    asm("v_cvt_pk_bf16_f32 %0, %1, %2" : "=v"(d0) : "v"(p[0]),  "v"(p[1]));
    asm("v_cvt_pk_bf16_f32 %0, %1, %2" : "=v"(d1) : "v"(p[2]),  "v"(p[3]));
    asm("v_cvt_pk_bf16_f32 %0, %1, %2" : "=v"(d2) : "v"(p[4]),  "v"(p[5]));
    asm("v_cvt_pk_bf16_f32 %0, %1, %2" : "=v"(d3) : "v"(p[6]),  "v"(p[7]));
    asm("v_cvt_pk_bf16_f32 %0, %1, %2" : "=v"(d4) : "v"(p[8]),  "v"(p[9]));
    asm("v_cvt_pk_bf16_f32 %0, %1, %2" : "=v"(d5) : "v"(p[10]), "v"(p[11]));
    asm("v_cvt_pk_bf16_f32 %0, %1, %2" : "=v"(d6) : "v"(p[12]), "v"(p[13]));
    asm("v_cvt_pk_bf16_f32 %0, %1, %2" : "=v"(d7) : "v"(p[14]), "v"(p[15]));
    asm("v_permlane32_swap_b32 %0, %1" : "+v"(d0), "+v"(d2));
    asm("v_permlane32_swap_b32 %0, %1" : "+v"(d1), "+v"(d3));
    asm("v_permlane32_swap_b32 %0, %1" : "+v"(d4), "+v"(d6));
    asm("v_permlane32_swap_b32 %0, %1" : "+v"(d5), "+v"(d7));
    union { unsigned u[4]; bf16x8 v; } pu0, pu1;
    pu0.u[0] = d0; pu0.u[1] = d1; pu0.u[2] = d2; pu0.u[3] = d3;
    pu1.u[0] = d4; pu1.u[1] = d5; pu1.u[2] = d6; pu1.u[3] = d7;

    // O += P . V  over this wave's m-half
    __builtin_amdgcn_s_setprio(1);
#pragma unroll
    for (int t = 0; t < 4; ++t) {
      bf16x8 bv0 = *(const bf16x8*)(vB + t * 4096 + vro);
      oacc[t] = __builtin_amdgcn_mfma_f32_32x32x16_bf16(pu0.v, bv0, oacc[t], 0, 0, 0);
      bf16x8 bv1 = *(const bf16x8*)(vB + t * 4096 + (vro ^ 32));
      oacc[t] = __builtin_amdgcn_mfma_f32_32x32x16_bf16(pu1.v, bv1, oacc[t], 0, 0, 0);
    }
    __builtin_amdgcn_s_setprio(0);
  }
#undef STAGE

  float lsum = (ls[0] + ls[1]) + (ls[2] + ls[3]);
  // merge q2 halves of the row sum: lane (l31,*) -> sum over this wave's 32 m
  lsum += __shfl_xor(lsum, 32, 64);

  // combine the two m-halves through LDS, normalize, coalesced store
  __syncthreads();                          // all tile reads done before aliasing
  float* cb  = (float*)smem;                // [2][64][64] partials = 32768 B
  float* cbL = (float*)(smem + 32768);      // [2][64] row sums
  if (w_m == 1) {
    float* my = cb + w_q * 4096;
#pragma unroll
    for (int t = 0; t < 4; ++t)
#pragma unroll
      for (int r = 0; r < 16; ++r)
        my[(t * 16 + r) * 64 + lane] = oacc[t][r];
  }
  cbL[w_m * 64 + w_q * 32 + l31] = lsum;    // both q2 lanes write same value
  __syncthreads();
  if (w_m == 0) {
    const float* pr = cb + w_q * 4096;
    float linv[16];
#pragma unroll
    for (int r = 0; r < 16; ++r) {
      int qr = (r & 3) + ((r >> 2) << 3) + (q2 << 2);
      linv[r] = 1.0f / (cbL[w_q * 32 + qr] + cbL[64 + w_q * 32 + qr]);
    }
    float* ob = out + ((size_t)(b * SEQ) + q0) * DIM;
#pragma unroll
    for (int t = 0; t < 4; ++t)
#pragma unroll
      for (int r = 0; r < 16; ++r) {
        int qr = (r & 3) + ((r >> 2) << 3) + (q2 << 2);
        ob[(size_t)qr * DIM + t * 32 + l31] = (oacc[t][r] + pr[(t * 16 + r) * 64 + lane]) * linv[r];
      }
  }
}

extern "C" void kernel_launch(void* const* d_in, const int* in_sizes, int n_in,
                              void* d_out, int out_size, void* d_ws, size_t ws_size,
                              hipStream_t stream) {
  const float* Q = (const float*)d_in[0];
  const float* K = (const float*)d_in[1];
  const float* V = (const float*)d_in[2];
  float* out = (float*)d_out;

  const size_t elems = (size_t)BATCH * SEQ * DIM;   // 4,194,304
  unsigned short* Kb = (unsigned short*)d_ws;       // 8 MB
  unsigned short* Vt = Kb + elems;                  // 8 MB (ws >= 16 MB)

  const double TEMPERATURE = 11.313708498984761;
  const float scale = (float)(1.4426950408889634 / TEMPERATURE);  // log2(e)/temp on K

  prep_kernel<<<3072, 256, 0, stream>>>(K, V, Kb, Vt, scale);
  attn_kernel<<<dim3(BATCH, SEQ / 64), 256, 0, stream>>>(Q, Kb, Vt, out);
}

// Round 4
// 132.550 us; speedup vs baseline: 1.0394x; 1.0190x over previous
//
#include <hip/hip_runtime.h>

// b=16, n=m=2048, d=dv=128, fp32 in/out, temp=sqrt(128).
// Prep: K -> bf16 scaled by log2e/temp; V -> Vt[b][dv][m] bf16. Q cast in-kernel.
// Attention: swapped S^T = K.Q^T via 32x32x16 bf16 MFMA, P = exp2(S),
// P->A-frag via v_cvt_pk_bf16_f32 + v_permlane32_swap_b32, PV accumulate.
// K/V staged by global_load_lds, double-buffered.
// Round-4: T3/T4 counted-vmcnt schedule — NO vmcnt(0) drain in the main loop.
//   bar1: s_waitcnt vmcnt(4) [K(t) landed, V(t) flying] + raw s_barrier
//   QK(t) ; STAGE(t+1) ; softmax(t)
//   bar2: s_waitcnt vmcnt(8) [V(t) landed, K/V(t+1) flying] + raw s_barrier
//   PV(t)
// Staging stays in flight across both barriers (previous rounds' __syncthreads
// forced a full vmcnt(0) drain convoy every tile — the dominant stall).
// Counts kept uniform by wrap-staging tile 0 on the last iter (drained by the
// epilogue __syncthreads). sched_barrier(0) + "memory" clobbers fence motion.
// Block = 4 waves: 2 q-waves (BQ=64) x 2 m-waves (BK=64 split 32/32).
// Grid 16x32 = 512 blocks -> 2 blocks/CU (64KB LDS), 8 waves/CU.

#define BATCH 16
#define SEQ   2048
#define DIM   128
#define NT    (SEQ / 64)

typedef short bf16x8 __attribute__((ext_vector_type(8)));
typedef float f32x16 __attribute__((ext_vector_type(16)));

static __device__ __forceinline__ unsigned pk2(float lo, float hi) {
  union { float f; unsigned u; } a, b;
  a.f = lo; b.f = hi;
  return ((b.u + 0x8000u) & 0xffff0000u) | ((a.u + 0x8000u) >> 16);
}
static __device__ __forceinline__ float fast_exp2(float x) {
#if __has_builtin(__builtin_amdgcn_exp2f)
  return __builtin_amdgcn_exp2f(x);
#else
  return exp2f(x);
#endif
}

typedef __attribute__((address_space(1))) const unsigned int g_u32;
typedef __attribute__((address_space(3))) unsigned int l_u32;
static __device__ __forceinline__ void gl2lds16(const unsigned short* g, unsigned short* l) {
  // per-lane global src; wave-uniform LDS base, HW writes base + lane*16
  __builtin_amdgcn_global_load_lds((g_u32*)g, (l_u32*)l, 16, 0, 0);
}

// ---- fused preprocess: blocks [0,2048): K cvt+scale; [2048,3072): V transpose ----
__global__ __launch_bounds__(256)
void prep_kernel(const float* __restrict__ K, const float* __restrict__ V,
                 unsigned short* __restrict__ Kb, unsigned short* __restrict__ Vt,
                 float scale) {
  const int bx = blockIdx.x, tid = threadIdx.x;
  if (bx < 2048) {
    size_t idx = (size_t)bx * 256 + tid;
    const float4* kf = (const float4*)K;
    float4 a = kf[idx * 2], c = kf[idx * 2 + 1];
    uint4 o;
    o.x = pk2(a.x * scale, a.y * scale);
    o.y = pk2(a.z * scale, a.w * scale);
    o.z = pk2(c.x * scale, c.y * scale);
    o.w = pk2(c.z * scale, c.w * scale);
    ((uint4*)Kb)[idx] = o;
  } else {
    __shared__ float tile[128][33];
    const int vb = bx - 2048;                 // 1024 blocks
    const int b = vb >> 6, r = vb & 63;
    const int m0 = (r & 15) * 128, d0 = (r >> 4) * 32;
    const int c = tid & 7, mr = tid >> 3;
    const float* src = V + ((size_t)(b * SEQ) + m0) * DIM + d0;
#pragma unroll
    for (int it = 0; it < 4; ++it) {
      int m = it * 32 + mr;
      float4 x = *(const float4*)(src + (size_t)m * DIM + c * 4);
      tile[m][c * 4 + 0] = x.x; tile[m][c * 4 + 1] = x.y;
      tile[m][c * 4 + 2] = x.z; tile[m][c * 4 + 3] = x.w;
    }
    __syncthreads();
    const int dr = tid >> 3, s = tid & 7;
    unsigned short* dst = Vt + ((size_t)(b * DIM) + d0 + dr) * SEQ + m0;
#pragma unroll
    for (int it = 0; it < 2; ++it) {
      int slot = it * 8 + s;
      uint4 o;
      o.x = pk2(tile[slot * 8 + 0][dr], tile[slot * 8 + 1][dr]);
      o.y = pk2(tile[slot * 8 + 2][dr], tile[slot * 8 + 3][dr]);
      o.z = pk2(tile[slot * 8 + 4][dr], tile[slot * 8 + 5][dr]);
      o.w = pk2(tile[slot * 8 + 6][dr], tile[slot * 8 + 7][dr]);
      *(uint4*)(dst + slot * 8) = o;
    }
  }
}

// ---- main flash attention ----
// LDS (bytes): K bufs [0,16384) [16384,32768); V bufs [32768,49152) [49152,65536)
// K buf: 64 rows x 256B linear, [row][x] holds K[m0+row][x ^ ((row&15)<<4)]
// V buf: 128 rows x 128B linear, [row][x] holds Vt[row][m0 + (x ^ ((row&7)<<4))/2]
// Epilogue (after barrier) aliases: cb f32[2][4096] @0, cbL f32[2][64] @32768.

__global__ __launch_bounds__(256, 2)
void attn_kernel(const float* __restrict__ Qf,
                 const unsigned short* __restrict__ Kb,
                 const unsigned short* __restrict__ Vtb,
                 float* __restrict__ out) {
  __shared__ __align__(1024) unsigned char smem[65536];
  unsigned short* sm16 = (unsigned short*)smem;

  const int tid  = threadIdx.x;
  const int wv   = tid >> 6;
  const int w_q  = wv & 1;                  // q-subtile (32 rows)
  const int w_m  = wv >> 1;                 // m-half (32 cols) of the 64-tile
  const int lane = tid & 63;
  const int l31  = lane & 31;
  const int q2   = lane >> 5;
  const int b    = blockIdx.x;
  const int q0   = blockIdx.y * 64 + w_q * 32;

  const unsigned short* kb = Kb  + (size_t)b * SEQ * DIM;   // [m][d], pre-scaled
  const unsigned short* vb = Vtb + (size_t)b * SEQ * DIM;   // [dv][m]

  // Q fragments (B-operand of swapped QK^T): lane (l31,q2) holds Q[q0+l31][c*16+q2*8+j]
  bf16x8 aq[8];
  {
    const float* qp = Qf + ((size_t)(b * SEQ) + q0 + l31) * DIM + q2 * 8;
#pragma unroll
    for (int c = 0; c < 8; ++c) {
      float4 x = *(const float4*)(qp + c * 16);
      float4 y = *(const float4*)(qp + c * 16 + 4);
      union { unsigned i[4]; bf16x8 v; } u;
      u.i[0] = pk2(x.x, x.y); u.i[1] = pk2(x.z, x.w);
      u.i[2] = pk2(y.x, y.y); u.i[3] = pk2(y.z, y.w);
      aq[c] = u.v;
    }
  }

  // staging source offsets (ushort units); LDS dest linear, global src pre-swizzled
  unsigned kgo[4], vgo[4];
#pragma unroll
  for (int i = 0; i < 4; ++i) {
    int ch = wv * 4 + i;
    int krow = ch * 4 + (lane >> 4);
    kgo[i] = (unsigned)(krow * 128) + ((((lane & 15) << 4) ^ ((krow & 15) << 4)) >> 1);
    int vrow = ch * 8 + (lane >> 3);
    vgo[i] = (unsigned)(vrow * 2048) + ((((lane & 7) << 4) ^ ((vrow & 7) << 4)) >> 1);
  }

  // swizzled read base offsets (bytes, within a buffer)
  const int kro = ((w_m * 32 + l31) << 8) + ((q2 << 4) ^ ((l31 & 15) << 4));
  const int vro = (l31 << 7) + (((w_m << 6) + (q2 << 4)) ^ ((l31 & 7) << 4));

  f32x16 oacc[4];
#pragma unroll
  for (int t = 0; t < 4; ++t)
#pragma unroll
    for (int i = 0; i < 16; ++i) oacc[t][i] = 0.0f;
  float ls[4] = {0.0f, 0.0f, 0.0f, 0.0f};

  // STAGE issues 4 K-loads FIRST, then 4 V-loads (order matters for the
  // counted vmcnt scheme: oldest outstanding = K chunk).
#define STAGE(TK, BUF) do {                                                  \
    const unsigned short* kt_b = kb + ((size_t)(TK) << 13);                  \
    const unsigned short* vt_b = vb + ((TK) << 6);                           \
    unsigned short* kd = sm16 + (((BUF) + wv * 4096) >> 1);                  \
    unsigned short* vd = sm16 + ((32768 + (BUF) + wv * 4096) >> 1);          \
    _Pragma("unroll")                                                        \
    for (int i = 0; i < 4; ++i) gl2lds16(kt_b + kgo[i], kd + i * 512);       \
    _Pragma("unroll")                                                        \
    for (int i = 0; i < 4; ++i) gl2lds16(vt_b + vgo[i], vd + i * 512);       \
  } while (0)

  STAGE(0, 0);

  for (int kt = 0; kt < NT; ++kt) {
    const int cur = (kt & 1) << 14;
    // ---- bar1: K(kt) landed for ALL waves; V(kt) + anything newer may fly ----
    asm volatile("s_waitcnt vmcnt(4)" ::: "memory");
    __builtin_amdgcn_s_barrier();
    __builtin_amdgcn_sched_barrier(0);

    const unsigned char* kB = smem + cur;
    const unsigned char* vB = smem + 32768 + cur;

    // S^T = K . Q^T : two independent 4-deep MFMA chains, merged at the end.
    // lane (l31,q2) holds S[q=l31][m=(r&3)+8*(r>>2)+4*q2]
    f32x16 se, so;
#pragma unroll
    for (int i = 0; i < 16; ++i) { se[i] = 0.0f; so[i] = 0.0f; }
    __builtin_amdgcn_s_setprio(1);
#pragma unroll
    for (int c = 0; c < 4; ++c) {
      bf16x8 b0 = *(const bf16x8*)(kB + (kro ^ ((2 * c) << 5)));
      se = __builtin_amdgcn_mfma_f32_32x32x16_bf16(b0, aq[2 * c], se, 0, 0, 0);
      bf16x8 b1 = *(const bf16x8*)(kB + (kro ^ ((2 * c + 1) << 5)));
      so = __builtin_amdgcn_mfma_f32_32x32x16_bf16(b1, aq[2 * c + 1], so, 0, 0, 0);
    }
    __builtin_amdgcn_s_setprio(0);
    __builtin_amdgcn_sched_barrier(0);

    // prefetch next tile into the other buffer; stays in flight across both
    // barriers and the next QK. Wrap to tile 0 at the end (keeps per-wave
    // vmcnt counts uniform; drained by the epilogue __syncthreads).
    STAGE((kt + 1) & (NT - 1), 16384 - cur);
    __builtin_amdgcn_sched_barrier(0);

    // P = exp2(S); partial row sums in 4 independent accumulators
    float p[16];
#pragma unroll
    for (int i = 0; i < 16; ++i) p[i] = fast_exp2(se[i] + so[i]);
#pragma unroll
    for (int i = 0; i < 4; ++i) {
      ls[0] += p[4 * i + 0]; ls[1] += p[4 * i + 1];
      ls[2] += p[4 * i + 2]; ls[3] += p[4 * i + 3];
    }

    // P -> PV A-fragments fully in-register: cvt_pk pairs + permlane32_swap
    unsigned d0, d1, d2, d3, d4, d5, d6, d7;
    asm("v_cvt_pk_bf16_f32 %0, %1, %2" : "=v"(d0) : "v"(p[0]),  "v"(p[1]));
    asm("v_cvt_pk_bf16_f32 %0, %1, %2" : "=v"(d1) : "v"(p[2]),  "v"(p[3]));
    asm("v_cvt_pk_bf16_f32 %0, %1, %2" : "=v"(d2) : "v"(p[4]),  "v"(p[5]));
    asm("v_cvt_pk_bf16_f32 %0, %1, %2" : "=v"(d3) : "v"(p[6]),  "v"(p[7]));
    asm("v_cvt_pk_bf16_f32 %0, %1, %2" : "=v"(d4) : "v"(p[8]),  "v"(p[9]));
    asm("v_cvt_pk_bf16_f32 %0, %1, %2" : "=v"(d5) : "v"(p[10]), "v"(p[11]));
    asm("v_cvt_pk_bf16_f32 %0, %1, %2" : "=v"(d6) : "v"(p[12]), "v"(p[13]));
    asm("v_cvt_pk_bf16_f32 %0, %1, %2" : "=v"(d7) : "v"(p[14]), "v"(p[15]));
    asm("v_permlane32_swap_b32 %0, %1" : "+v"(d0), "+v"(d2));
    asm("v_permlane32_swap_b32 %0, %1" : "+v"(d1), "+v"(d3));
    asm("v_permlane32_swap_b32 %0, %1" : "+v"(d4), "+v"(d6));
    asm("v_permlane32_swap_b32 %0, %1" : "+v"(d5), "+v"(d7));
    union { unsigned u[4]; bf16x8 v; } pu0, pu1;
    pu0.u[0] = d0; pu0.u[1] = d1; pu0.u[2] = d2; pu0.u[3] = d3;
    pu1.u[0] = d4; pu1.u[1] = d5; pu1.u[2] = d6; pu1.u[3] = d7;

    // ---- bar2: V(kt) landed for ALL waves; K/V(kt+1) (8 loads) still fly ----
    asm volatile("s_waitcnt vmcnt(8)" ::: "memory");
    __builtin_amdgcn_s_barrier();
    __builtin_amdgcn_sched_barrier(0);

    // O += P . V  over this wave's m-half
    __builtin_amdgcn_s_setprio(1);
#pragma unroll
    for (int t = 0; t < 4; ++t) {
      bf16x8 bv0 = *(const bf16x8*)(vB + t * 4096 + vro);
      oacc[t] = __builtin_amdgcn_mfma_f32_32x32x16_bf16(pu0.v, bv0, oacc[t], 0, 0, 0);
      bf16x8 bv1 = *(const bf16x8*)(vB + t * 4096 + (vro ^ 32));
      oacc[t] = __builtin_amdgcn_mfma_f32_32x32x16_bf16(pu1.v, bv1, oacc[t], 0, 0, 0);
    }
    __builtin_amdgcn_s_setprio(0);
    __builtin_amdgcn_sched_barrier(0);
  }
#undef STAGE

  float lsum = (ls[0] + ls[1]) + (ls[2] + ls[3]);
  // merge q2 halves of the row sum: lane (l31,*) -> sum over this wave's 32 m
  lsum += __shfl_xor(lsum, 32, 64);

  // combine the two m-halves through LDS, normalize, coalesced store
  __syncthreads();                          // drains wrap-stage; all tile reads done
  float* cb  = (float*)smem;                // [2][64][64] partials = 32768 B
  float* cbL = (float*)(smem + 32768);      // [2][64] row sums
  if (w_m == 1) {
    float* my = cb + w_q * 4096;
#pragma unroll
    for (int t = 0; t < 4; ++t)
#pragma unroll
      for (int r = 0; r < 16; ++r)
        my[(t * 16 + r) * 64 + lane] = oacc[t][r];
  }
  cbL[w_m * 64 + w_q * 32 + l31] = lsum;    // both q2 lanes write same value
  __syncthreads();
  if (w_m == 0) {
    const float* pr = cb + w_q * 4096;
    float linv[16];
#pragma unroll
    for (int r = 0; r < 16; ++r) {
      int qr = (r & 3) + ((r >> 2) << 3) + (q2 << 2);
      linv[r] = 1.0f / (cbL[w_q * 32 + qr] + cbL[64 + w_q * 32 + qr]);
    }
    float* ob = out + ((size_t)(b * SEQ) + q0) * DIM;
#pragma unroll
    for (int t = 0; t < 4; ++t)
#pragma unroll
      for (int r = 0; r < 16; ++r) {
        int qr = (r & 3) + ((r >> 2) << 3) + (q2 << 2);
        ob[(size_t)qr * DIM + t * 32 + l31] = (oacc[t][r] + pr[(t * 16 + r) * 64 + lane]) * linv[r];
      }
  }
}

extern "C" void kernel_launch(void* const* d_in, const int* in_sizes, int n_in,
                              void* d_out, int out_size, void* d_ws, size_t ws_size,
                              hipStream_t stream) {
  const float* Q = (const float*)d_in[0];
  const float* K = (const float*)d_in[1];
  const float* V = (const float*)d_in[2];
  float* out = (float*)d_out;

  const size_t elems = (size_t)BATCH * SEQ * DIM;   // 4,194,304
  unsigned short* Kb = (unsigned short*)d_ws;       // 8 MB
  unsigned short* Vt = Kb + elems;                  // 8 MB (ws >= 16 MB)

  const double TEMPERATURE = 11.313708498984761;
  const float scale = (float)(1.4426950408889634 / TEMPERATURE);  // log2(e)/temp on K

  prep_kernel<<<3072, 256, 0, stream>>>(K, V, Kb, Vt, scale);
  attn_kernel<<<dim3(BATCH, SEQ / 64), 256, 0, stream>>>(Q, Kb, Vt, out);
}